// Round 12
// baseline (188.356 us; speedup 1.0000x reference)
//
#include <hip/hip_runtime.h>
#include <stdint.h>

// Problem constants (from reference setup_inputs)
#define BB 4
#define SS 512
#define EE 64
#define VV 50257
#define KK 250              // k_val
#define NROWS (BB * SS)     // 2048
#define NBLK (NROWS / 2)    // 1024 blocks, 2 rows each (pipelined)
#define CAP 1024            // per-row LDS candidate capacity (8 KB)
// STEP_SIZE = 0.1 -> multiply by 10; TEMP = 1.0 -> no-op

// Float-domain pre-filter threshold. P(N(0,1) >= 2.4) = 0.0082 -> E[412]/row,
// sigma ~20. Correctness does NOT depend on it: rows outside [KK,CAP] take the
// exact full-row fallback; rows with n in (512,CAP] take a deferred wide scan.
#define THRF 2.4f

typedef float float4n __attribute__((ext_vector_type(4)));
typedef unsigned long long u64;

__device__ __forceinline__ unsigned fkey(float f) {
    // monotonic map: larger float -> larger unsigned
    unsigned u = __float_as_uint(f);
    return (u & 0x80000000u) ? ~u : (u | 0x80000000u);
}

// Streaming filter over one row with a thread subset (rtid < rstride).
__device__ __forceinline__ void stream_row(const float* __restrict__ rp,
                                           u64* buf, unsigned* cnt,
                                           unsigned rtid, unsigned rstride,
                                           unsigned p, unsigned F, unsigned tail0)
{
    const float4n* rp4 = (const float4n*)(rp + p);
    auto emit = [&](float f, unsigned col) {
        if (f >= THRF) {
            unsigned q = atomicAdd(cnt, 1u);
            if (q < CAP) buf[q] = ((u64)fkey(f) << 32) | (unsigned)(~col);
        }
    };
    if (rtid < p) emit(rp[rtid], rtid);
    unsigned i = rtid;
    for (; i + 3u * rstride < F; i += 4u * rstride) {   // 4 loads in flight
        float4n a = __builtin_nontemporal_load(&rp4[i]);
        float4n b = __builtin_nontemporal_load(&rp4[i + rstride]);
        float4n c = __builtin_nontemporal_load(&rp4[i + 2u * rstride]);
        float4n d = __builtin_nontemporal_load(&rp4[i + 3u * rstride]);
        float t0 = fmaxf(fmaxf(a.x, a.y), a.z);
        float t1 = fmaxf(fmaxf(a.w, b.x), b.y);
        float t2 = fmaxf(fmaxf(b.z, b.w), c.x);
        float t3 = fmaxf(fmaxf(c.y, c.z), c.w);
        float t4 = fmaxf(fmaxf(d.x, d.y), d.z);
        float u0 = fmaxf(fmaxf(t0, t1), t2);
        float u1 = fmaxf(fmaxf(t3, t4), d.w);
        if (fmaxf(u0, u1) >= THRF) {
            unsigned c0 = p + 4u*i, c1 = p + 4u*(i + rstride);
            unsigned c2 = p + 4u*(i + 2u*rstride), c3 = p + 4u*(i + 3u*rstride);
            emit(a.x, c0+0); emit(a.y, c0+1); emit(a.z, c0+2); emit(a.w, c0+3);
            emit(b.x, c1+0); emit(b.y, c1+1); emit(b.z, c1+2); emit(b.w, c1+3);
            emit(c.x, c2+0); emit(c.y, c2+1); emit(c.z, c2+2); emit(c.w, c2+3);
            emit(d.x, c3+0); emit(d.y, c3+1); emit(d.z, c3+2); emit(d.w, c3+3);
        }
    }
    for (; i < F; i += rstride) {
        float4n a = __builtin_nontemporal_load(&rp4[i]);
        if (fmaxf(fmaxf(a.x, a.y), fmaxf(a.z, a.w)) >= THRF) {
            unsigned c0 = p + 4u*i;
            emit(a.x, c0+0); emit(a.y, c0+1); emit(a.z, c0+2); emit(a.w, c0+3);
        }
    }
    for (unsigned t = tail0 + rtid; t < VV; t += rstride) emit(rp[t], t);
}

__device__ __forceinline__ void write_out(u64 ck, unsigned r, int row,
    const float* gxs, const float* cbs, float gxcb, float cbn,
    const float* __restrict__ W, float* __restrict__ out0, float* __restrict__ out1)
{
    unsigned v = ~((unsigned)ck);
    const float4* Wv = (const float4*)(W + (size_t)v * EE);
    float d1 = 0.f, d2 = 0.f, wn = 0.f;
    #pragma unroll
    for (int j = 0; j < 16; ++j) {
        float4 w = Wv[j];
        float a0 = gxs[4*j+0], a1 = gxs[4*j+1], a2 = gxs[4*j+2], a3 = gxs[4*j+3];
        float b0 = cbs[4*j+0], b1 = cbs[4*j+1], b2 = cbs[4*j+2], b3 = cbs[4*j+3];
        d1 += a0*w.x + a1*w.y + a2*w.z + a3*w.w;
        d2 += b0*w.x + b1*w.y + b2*w.z + b3*w.w;
        wn += w.x*w.x + w.y*w.y + w.z*w.z + w.w*w.w;
    }
    // dist = 0.5*(t1_1 - t1_2) + (t2_1 - 2*t2_2 + t2_3)/0.1 ; out = -dist / TEMP
    float unf = -(0.5f * (d1 - gxcb) + (wn - 2.0f * d2 + cbn) * 10.0f);
    out0[(size_t)row * KK + r] = unf;
    out1[(size_t)row * KK + r] = (float)v;
}

// Rank-scatter tail: rank_i = #{j: key_j > key_i}; keys unique -> permutation.
// No internal barriers (read-only scan; buf padded to x4 beforehand).
template<int SLOTS>
__device__ __forceinline__ void tail_scan(const u64* buf, unsigned n,
    unsigned rtid, unsigned rstride, int row,
    const float* gxs, const float* cbs, float gxcb, float cbn,
    const float* __restrict__ W, float* __restrict__ out0, float* __restrict__ out1)
{
    const unsigned P4 = (n + 3u) & ~3u;
    u64 k[SLOTS]; unsigned r[SLOTS];
    #pragma unroll
    for (int s = 0; s < SLOTS; ++s) {
        unsigned idx = rtid + (unsigned)s * rstride;
        k[s] = (idx < n) ? buf[idx] : 0ull;
        r[s] = 0u;
    }
    for (unsigned j = 0; j < P4; j += 4u) {          // broadcast reads, conflict-free
        u64 a = buf[j], b = buf[j+1], c = buf[j+2], d = buf[j+3];
        #pragma unroll
        for (int s = 0; s < SLOTS; ++s)
            r[s] += (unsigned)(a > k[s]) + (unsigned)(b > k[s])
                  + (unsigned)(c > k[s]) + (unsigned)(d > k[s]);
    }
    #pragma unroll
    for (int s = 0; s < SLOTS; ++s) {
        unsigned idx = rtid + (unsigned)s * rstride;
        if (idx < n && r[s] < KK) write_out(k[s], r[s], row, gxs, cbs, gxcb, cbn, W, out0, out1);
    }
}

__global__ __launch_bounds__(256)
void langevin_fused2(const float* __restrict__ gx,
                     const float* __restrict__ cb,
                     const float* __restrict__ W,
                     const float* __restrict__ lg,
                     float* __restrict__ out0,
                     float* __restrict__ out1)
{
    __shared__ u64 bufA[CAP], bufB[CAP];         // 16 KB
    __shared__ float gxA[EE], cbA[EE], gxB[EE], cbB[EE];
    __shared__ float sDots[4];                   // gxcbA, cbnA, gxcbB, cbnB
    __shared__ unsigned cntA, cntB, sTbin;

    const int tid  = threadIdx.x;
    const int row0 = blockIdx.x * 2, row1 = row0 + 1;
    const float* rp0 = lg + (size_t)row0 * VV;
    const float* rp1 = lg + (size_t)row1 * VV;

    if (tid < 64) {          // wave 0 lanes: row0 scalars + dots
        float a = gx[(size_t)row0 * EE + tid], b = cb[(size_t)row0 * EE + tid];
        gxA[tid] = a; cbA[tid] = b;
        float q1 = a * b, q2 = b * b;
        #pragma unroll
        for (int d = 32; d > 0; d >>= 1) { q1 += __shfl_xor(q1, d, 64); q2 += __shfl_xor(q2, d, 64); }
        if (tid == 0) { sDots[0] = q1; sDots[1] = q2; }
    } else if (tid < 128) {  // wave 1 lanes: row1 scalars + dots
        int t = tid - 64;
        float a = gx[(size_t)row1 * EE + t], b = cb[(size_t)row1 * EE + t];
        gxB[t] = a; cbB[t] = b;
        float q1 = a * b, q2 = b * b;
        #pragma unroll
        for (int d = 32; d > 0; d >>= 1) { q1 += __shfl_xor(q1, d, 64); q2 += __shfl_xor(q2, d, 64); }
        if (t == 0) { sDots[2] = q1; sDots[3] = q2; }
    }
    if (tid == 0)   cntA = 0u;
    if (tid == 255) cntB = 0u;
    __syncthreads();

    const unsigned p0  = (4u - ((unsigned)((size_t)row0 * VV) & 3u)) & 3u;
    const unsigned F0g = (VV - p0) >> 2;
    const unsigned t00 = p0 + 4u * F0g;
    const unsigned p1g = (4u - ((unsigned)((size_t)row1 * VV) & 3u)) & 3u;
    const unsigned F1g = (VV - p1g) >> 2;
    const unsigned t10 = p1g + 4u * F1g;

    // ---- stage 0: all 4 waves stream row0 -> bufA ----
    stream_row(rp0, bufA, &cntA, (unsigned)tid, 256u, p0, F0g, t00);
    __syncthreads();
    const unsigned n0 = cntA;
    const bool ok0 = (n0 >= KK && n0 <= CAP);
    if (ok0) for (unsigned j = n0 + tid; j < ((n0 + 3u) & ~3u); j += 256u) bufA[j] = 0ull;
    __syncthreads();

    // ---- stage 1: waves 0-1 tail row0 (hidden) | waves 2-3 stream row1 -> bufB ----
    if (tid < 128) {
        if (n0 >= KK && n0 <= 512u)
            tail_scan<4>(bufA, n0, (unsigned)tid, 128u, row0, gxA, cbA, sDots[0], sDots[1], W, out0, out1);
    } else {
        stream_row(rp1, bufB, &cntB, (unsigned)(tid - 128), 128u, p1g, F1g, t10);
    }
    __syncthreads();
    const unsigned n1 = cntB;
    const bool ok1 = (n1 >= KK && n1 <= CAP);
    if (ok1) for (unsigned j = n1 + tid; j < ((n1 + 3u) & ~3u); j += 256u) bufB[j] = 0ull;
    __syncthreads();

    // ---- stage 2: all 4 waves tail row1 ----
    if (n1 >= KK && n1 <= 512u)
        tail_scan<2>(bufB, n1, (unsigned)tid, 256u, row1, gxB, cbB, sDots[2], sDots[3], W, out0, out1);
    else if (ok1)   // 512 < n1 <= CAP (rare)
        tail_scan<4>(bufB, n1, (unsigned)tid, 256u, row1, gxB, cbB, sDots[2], sDots[3], W, out0, out1);

    // deferred rare: row0 with 512 < n0 <= CAP (not handled in stage 1)
    if (ok0 && n0 > 512u)
        tail_scan<4>(bufA, n0, (unsigned)tid, 256u, row0, gxA, cbA, sDots[0], sDots[1], W, out0, out1);

    // ====== EXACT FALLBACKS (never taken on N(0,1) data); block-uniform ======
    if (!ok0) {
        unsigned* hist = (unsigned*)bufA;              // 1024 bins (4 KB)
        unsigned* csum = ((unsigned*)bufA) + 1024;     // 256 sums (1 KB)
        for (int j = tid; j < 1024; j += 256) hist[j] = 0u;
        if (tid == 0) cntA = 0u;
        __syncthreads();
        const float4n* rp4 = (const float4n*)(rp0 + p0);
        if (tid < (int)p0) atomicAdd(&hist[fkey(rp0[tid]) >> 22], 1u);
        for (unsigned j = tid; j < F0g; j += 256u) {
            float4n v = rp4[j];
            atomicAdd(&hist[fkey(v.x) >> 22], 1u); atomicAdd(&hist[fkey(v.y) >> 22], 1u);
            atomicAdd(&hist[fkey(v.z) >> 22], 1u); atomicAdd(&hist[fkey(v.w) >> 22], 1u);
        }
        for (unsigned t = t00 + tid; t < VV; t += 256u) atomicAdd(&hist[fkey(rp0[t]) >> 22], 1u);
        __syncthreads();
        csum[tid] = hist[tid*4] + hist[tid*4+1] + hist[tid*4+2] + hist[tid*4+3];
        __syncthreads();
        {
            unsigned g = 0;
            for (int u2 = tid + 1; u2 < 256; ++u2) g += csum[u2];
            unsigned cs = csum[tid];
            if (g < KK && g + cs >= KK) {
                unsigned cum = g;
                #pragma unroll
                for (int b2 = 3; b2 >= 0; --b2) {
                    unsigned c2 = hist[tid*4 + b2];
                    if (cum + c2 >= KK) { sTbin = (unsigned)(tid*4 + b2); break; }
                    cum += c2;
                }
            }
        }
        __syncthreads();
        const unsigned keyT = sTbin << 22;
        __syncthreads();                               // hist/csum dead -> bufA reusable
        auto emit2 = [&](float f, unsigned col) {
            unsigned k = fkey(f);
            if (k >= keyT) {
                unsigned q = atomicAdd(&cntA, 1u);
                if (q < CAP) bufA[q] = ((u64)k << 32) | (unsigned)(~col);
            }
        };
        if (tid < (int)p0) emit2(rp0[tid], tid);
        for (unsigned j = tid; j < F0g; j += 256u) {
            float4n v = rp4[j]; unsigned ia = p0 + 4u*j;
            emit2(v.x, ia+0); emit2(v.y, ia+1); emit2(v.z, ia+2); emit2(v.w, ia+3);
        }
        for (unsigned t = t00 + tid; t < VV; t += 256u) emit2(rp0[t], t);
        __syncthreads();
        unsigned nf = cntA; if (nf > CAP) nf = CAP;
        for (unsigned j = nf + tid; j < ((nf + 3u) & ~3u); j += 256u) bufA[j] = 0ull;
        __syncthreads();
        tail_scan<4>(bufA, nf, (unsigned)tid, 256u, row0, gxA, cbA, sDots[0], sDots[1], W, out0, out1);
    }
    if (!ok1) {
        unsigned* hist = (unsigned*)bufB;
        unsigned* csum = ((unsigned*)bufB) + 1024;
        for (int j = tid; j < 1024; j += 256) hist[j] = 0u;
        if (tid == 0) cntB = 0u;
        __syncthreads();
        const float4n* rp4 = (const float4n*)(rp1 + p1g);
        if (tid < (int)p1g) atomicAdd(&hist[fkey(rp1[tid]) >> 22], 1u);
        for (unsigned j = tid; j < F1g; j += 256u) {
            float4n v = rp4[j];
            atomicAdd(&hist[fkey(v.x) >> 22], 1u); atomicAdd(&hist[fkey(v.y) >> 22], 1u);
            atomicAdd(&hist[fkey(v.z) >> 22], 1u); atomicAdd(&hist[fkey(v.w) >> 22], 1u);
        }
        for (unsigned t = t10 + tid; t < VV; t += 256u) atomicAdd(&hist[fkey(rp1[t]) >> 22], 1u);
        __syncthreads();
        csum[tid] = hist[tid*4] + hist[tid*4+1] + hist[tid*4+2] + hist[tid*4+3];
        __syncthreads();
        {
            unsigned g = 0;
            for (int u2 = tid + 1; u2 < 256; ++u2) g += csum[u2];
            unsigned cs = csum[tid];
            if (g < KK && g + cs >= KK) {
                unsigned cum = g;
                #pragma unroll
                for (int b2 = 3; b2 >= 0; --b2) {
                    unsigned c2 = hist[tid*4 + b2];
                    if (cum + c2 >= KK) { sTbin = (unsigned)(tid*4 + b2); break; }
                    cum += c2;
                }
            }
        }
        __syncthreads();
        const unsigned keyT = sTbin << 22;
        __syncthreads();
        auto emit2 = [&](float f, unsigned col) {
            unsigned k = fkey(f);
            if (k >= keyT) {
                unsigned q = atomicAdd(&cntB, 1u);
                if (q < CAP) bufB[q] = ((u64)k << 32) | (unsigned)(~col);
            }
        };
        if (tid < (int)p1g) emit2(rp1[tid], tid);
        for (unsigned j = tid; j < F1g; j += 256u) {
            float4n v = rp4[j]; unsigned ia = p1g + 4u*j;
            emit2(v.x, ia+0); emit2(v.y, ia+1); emit2(v.z, ia+2); emit2(v.w, ia+3);
        }
        for (unsigned t = t10 + tid; t < VV; t += 256u) emit2(rp1[t], t);
        __syncthreads();
        unsigned nf = cntB; if (nf > CAP) nf = CAP;
        for (unsigned j = nf + tid; j < ((nf + 3u) & ~3u); j += 256u) bufB[j] = 0ull;
        __syncthreads();
        tail_scan<4>(bufB, nf, (unsigned)tid, 256u, row1, gxB, cbB, sDots[2], sDots[3], W, out0, out1);
    }
}

extern "C" void kernel_launch(void* const* d_in, const int* in_sizes, int n_in,
                              void* d_out, int out_size, void* d_ws, size_t ws_size,
                              hipStream_t stream) {
    const float* gx = (const float*)d_in[0];      // [B,S,E]
    const float* cb = (const float*)d_in[1];      // [B,S,E]
    const float* W  = (const float*)d_in[2];      // [V,E]
    const float* lg = (const float*)d_in[3];      // [B,S,V]
    float* out0 = (float*)d_out;                       // filtered, 512000 floats
    float* out1 = out0 + (size_t)BB * SS * KK;         // ids as float, 512000

    hipLaunchKernelGGL(langevin_fused2, dim3(NBLK), dim3(256), 0, stream,
                       gx, cb, W, lg, out0, out1);
}

// Round 13
// 126.428 us; speedup vs baseline: 1.4898x; 1.4898x over previous
//
#include <hip/hip_runtime.h>
#include <stdint.h>

// Problem constants (from reference setup_inputs)
#define BB 4
#define SS 512
#define EE 64
#define VV 50257
#define KK 250              // k_val
#define NROWS (BB * SS)     // 2048
#define CAP 1024            // per-row LDS candidate capacity (8 KB)
// STEP_SIZE = 0.1 -> multiply by 10; TEMP = 1.0 -> no-op

// Float-domain pre-filter threshold. P(N(0,1) >= 2.4) = 0.0082 -> E[412]/row,
// sigma ~20. Correctness does NOT depend on it: rows outside [KK,CAP] take the
// in-kernel exact full-row fallback.
#define THRF 2.4f

typedef float float4n __attribute__((ext_vector_type(4)));
typedef unsigned long long u64;

__device__ __forceinline__ unsigned fkey(float f) {
    // monotonic map: larger float -> larger unsigned
    unsigned u = __float_as_uint(f);
    return (u & 0x80000000u) ? ~u : (u | 0x80000000u);
}

// ---------------- kernel 1: stream + rank-scatter, ids only ----------------
// One block per row (2048 blocks, 8/CU -> 32 streaming waves/CU preserved).
// Writes out1[row*KK + rank] = (float)id. No gx/cb/W usage at all.
__global__ __launch_bounds__(256)
void select_ids(const float* __restrict__ lg,
                float* __restrict__ out1)
{
    __shared__ u64 lbuf[CAP];                  // 8 KB; fallback hist aliases
    __shared__ unsigned lcnt, sTbin;

    const int row = blockIdx.x;
    const int tid = threadIdx.x;
    const float* rp = lg + (size_t)row * VV;

    if (tid == 0) lcnt = 0u;
    __syncthreads();

    const unsigned p  = (4u - ((unsigned)((size_t)row * VV) & 3u)) & 3u; // 16B-align peel
    const unsigned F  = (VV - p) >> 2;                                   // aligned float4s
    const unsigned tail0 = p + 4u * F;
    const float4n* rp4 = (const float4n*)(rp + p);

    auto emit = [&](float f, unsigned col) {
        if (f >= THRF) {
            unsigned q = atomicAdd(&lcnt, 1u);
            if (q < CAP) lbuf[q] = ((u64)fkey(f) << 32) | (unsigned)(~col);
        }
    };

    // ---- streaming filter: 4 loads in flight, 16-wide max guard ----
    if (tid < (int)p) emit(rp[tid], tid);
    unsigned i = tid;
    for (; i + 768u < F; i += 1024u) {
        float4n a = __builtin_nontemporal_load(&rp4[i]);
        float4n b = __builtin_nontemporal_load(&rp4[i + 256u]);
        float4n c = __builtin_nontemporal_load(&rp4[i + 512u]);
        float4n d = __builtin_nontemporal_load(&rp4[i + 768u]);
        float t0 = fmaxf(fmaxf(a.x, a.y), a.z);
        float t1 = fmaxf(fmaxf(a.w, b.x), b.y);
        float t2 = fmaxf(fmaxf(b.z, b.w), c.x);
        float t3 = fmaxf(fmaxf(c.y, c.z), c.w);
        float t4 = fmaxf(fmaxf(d.x, d.y), d.z);
        float u0 = fmaxf(fmaxf(t0, t1), t2);
        float u1 = fmaxf(fmaxf(t3, t4), d.w);
        if (fmaxf(u0, u1) >= THRF) {
            unsigned c0 = p + 4u*i, c1 = p + 4u*(i+256u), c2 = p + 4u*(i+512u), c3 = p + 4u*(i+768u);
            emit(a.x, c0+0); emit(a.y, c0+1); emit(a.z, c0+2); emit(a.w, c0+3);
            emit(b.x, c1+0); emit(b.y, c1+1); emit(b.z, c1+2); emit(b.w, c1+3);
            emit(c.x, c2+0); emit(c.y, c2+1); emit(c.z, c2+2); emit(c.w, c2+3);
            emit(d.x, c3+0); emit(d.y, c3+1); emit(d.z, c3+2); emit(d.w, c3+3);
        }
    }
    for (; i < F; i += 256u) {
        float4n a = __builtin_nontemporal_load(&rp4[i]);
        if (fmaxf(fmaxf(a.x, a.y), fmaxf(a.z, a.w)) >= THRF) {
            unsigned c0 = p + 4u*i;
            emit(a.x, c0+0); emit(a.y, c0+1); emit(a.z, c0+2); emit(a.w, c0+3);
        }
    }
    for (unsigned t = tail0 + tid; t < VV; t += 256u) emit(rp[t], t);
    __syncthreads();

    unsigned n = lcnt;

    if (n < KK || n > CAP) {
        // ====== EXACT FALLBACK (never taken on N(0,1) data) ======
        unsigned* hist = (unsigned*)lbuf;                 // 1024 bins (4 KB)
        unsigned* csum = ((unsigned*)lbuf) + 1024;        // 256 sums (1 KB)
        for (int j = tid; j < 1024; j += 256) hist[j] = 0u;
        __syncthreads();

        if (tid < (int)p) atomicAdd(&hist[fkey(rp[tid]) >> 22], 1u);
        for (unsigned j = tid; j < F; j += 256u) {
            float4n v = rp4[j];
            atomicAdd(&hist[fkey(v.x) >> 22], 1u); atomicAdd(&hist[fkey(v.y) >> 22], 1u);
            atomicAdd(&hist[fkey(v.z) >> 22], 1u); atomicAdd(&hist[fkey(v.w) >> 22], 1u);
        }
        for (unsigned t = tail0 + tid; t < VV; t += 256u) atomicAdd(&hist[fkey(rp[t]) >> 22], 1u);
        __syncthreads();

        csum[tid] = hist[tid*4] + hist[tid*4+1] + hist[tid*4+2] + hist[tid*4+3];
        __syncthreads();
        {
            unsigned g = 0;
            for (int u2 = tid + 1; u2 < 256; ++u2) g += csum[u2];
            unsigned cs = csum[tid];
            if (g < KK && g + cs >= KK) {
                unsigned cum = g;
                #pragma unroll
                for (int b2 = 3; b2 >= 0; --b2) {
                    unsigned c2 = hist[tid*4 + b2];
                    if (cum + c2 >= KK) { sTbin = (unsigned)(tid*4 + b2); break; }
                    cum += c2;
                }
            }
        }
        __syncthreads();
        const unsigned keyT = sTbin << 22;
        if (tid == 0) lcnt = 0u;
        __syncthreads();   // hist/csum dead -> lbuf reusable

        auto emit2 = [&](float f, unsigned col) {
            unsigned k = fkey(f);
            if (k >= keyT) {
                unsigned q = atomicAdd(&lcnt, 1u);
                if (q < CAP) lbuf[q] = ((u64)k << 32) | (unsigned)(~col);
            }
        };
        if (tid < (int)p) emit2(rp[tid], tid);
        for (unsigned j = tid; j < F; j += 256u) {
            float4n v = rp4[j];
            unsigned ia = p + 4u*j;
            emit2(v.x, ia+0); emit2(v.y, ia+1); emit2(v.z, ia+2); emit2(v.w, ia+3);
        }
        for (unsigned t = tail0 + tid; t < VV; t += 256u) emit2(rp[t], t);
        __syncthreads();
        n = lcnt;
        if (n > CAP) n = CAP;   // pathological mass-tie truncation
    }

    // ---- rank-scatter: rank_i = #{j: key_j > key_i}; unique keys -> permutation ----
    const unsigned P4 = (n + 3u) & ~3u;
    for (unsigned j = n + tid; j < P4; j += 256u) lbuf[j] = 0ull;
    __syncthreads();

    u64 k0 = ((unsigned)tid < n)        ? lbuf[tid]        : 0ull;
    u64 k1 = ((unsigned)tid + 256u < n) ? lbuf[tid + 256u] : 0ull;
    unsigned r0 = 0, r1 = 0;
    if (n <= 512u) {          // block-uniform: typical case, 2 slots
        for (unsigned j = 0; j < P4; j += 4) {
            u64 a = lbuf[j], b = lbuf[j+1], c = lbuf[j+2], d = lbuf[j+3];
            r0 += (a > k0) + (b > k0) + (c > k0) + (d > k0);
            r1 += (a > k1) + (b > k1) + (c > k1) + (d > k1);
        }
        if ((unsigned)tid < n        && r0 < KK) out1[(size_t)row * KK + r0] = (float)(~(unsigned)k0);
        if ((unsigned)tid + 256u < n && r1 < KK) out1[(size_t)row * KK + r1] = (float)(~(unsigned)k1);
    } else {
        u64 k2 = ((unsigned)tid + 512u < n) ? lbuf[tid + 512u] : 0ull;
        u64 k3 = ((unsigned)tid + 768u < n) ? lbuf[tid + 768u] : 0ull;
        unsigned r2 = 0, r3 = 0;
        for (unsigned j = 0; j < P4; j += 4) {
            u64 a = lbuf[j], b = lbuf[j+1], c = lbuf[j+2], d = lbuf[j+3];
            r0 += (a > k0) + (b > k0) + (c > k0) + (d > k0);
            r1 += (a > k1) + (b > k1) + (c > k1) + (d > k1);
            r2 += (a > k2) + (b > k2) + (c > k2) + (d > k2);
            r3 += (a > k3) + (b > k3) + (c > k3) + (d > k3);
        }
        if ((unsigned)tid < n        && r0 < KK) out1[(size_t)row * KK + r0] = (float)(~(unsigned)k0);
        if ((unsigned)tid + 256u < n && r1 < KK) out1[(size_t)row * KK + r1] = (float)(~(unsigned)k1);
        if ((unsigned)tid + 512u < n && r2 < KK) out1[(size_t)row * KK + r2] = (float)(~(unsigned)k2);
        if ((unsigned)tid + 768u < n && r3 < KK) out1[(size_t)row * KK + r3] = (float)(~(unsigned)k3);
    }
}

// ---------------- kernel 2: full-occupancy W-gather epilogue ----------------
// One block per row; reads ids back from out1 (float-stored, exact <= 2^24).
__global__ __launch_bounds__(256)
void epilogue_kernel(const float* __restrict__ gx,
                     const float* __restrict__ cb,
                     const float* __restrict__ W,
                     const float* __restrict__ ids,   // = out1
                     float* __restrict__ out0)
{
    __shared__ float gxs[EE], cbs[EE];
    __shared__ float sGxcb, sCbn;
    const int row = blockIdx.x;
    const int tid = threadIdx.x;

    if (tid < EE) {   // wave 0: row scalars + block-wide dots via shuffle reduce
        float a = gx[(size_t)row * EE + tid];
        float b = cb[(size_t)row * EE + tid];
        gxs[tid] = a; cbs[tid] = b;
        float p1 = a * b, p2 = b * b;
        #pragma unroll
        for (int d = 32; d > 0; d >>= 1) {
            p1 += __shfl_xor(p1, d, 64);
            p2 += __shfl_xor(p2, d, 64);
        }
        if (tid == 0) { sGxcb = p1; sCbn = p2; }
    }
    __syncthreads();

    if (tid < KK) {
        unsigned v = (unsigned)ids[(size_t)row * KK + tid];
        const float4* Wv = (const float4*)(W + (size_t)v * EE);
        float d1 = 0.f, d2 = 0.f, wn = 0.f;
        #pragma unroll
        for (int j = 0; j < 16; ++j) {
            float4 w = Wv[j];
            float a0 = gxs[4*j+0], a1 = gxs[4*j+1], a2 = gxs[4*j+2], a3 = gxs[4*j+3];
            float b0 = cbs[4*j+0], b1 = cbs[4*j+1], b2 = cbs[4*j+2], b3 = cbs[4*j+3];
            d1 += a0*w.x + a1*w.y + a2*w.z + a3*w.w;
            d2 += b0*w.x + b1*w.y + b2*w.z + b3*w.w;
            wn += w.x*w.x + w.y*w.y + w.z*w.z + w.w*w.w;
        }
        // dist = 0.5*(t1_1 - t1_2) + (t2_1 - 2*t2_2 + t2_3)/0.1 ; out = -dist / TEMP
        out0[(size_t)row * KK + tid] = -(0.5f * (d1 - sGxcb) + (wn - 2.0f * d2 + sCbn) * 10.0f);
    }
}

extern "C" void kernel_launch(void* const* d_in, const int* in_sizes, int n_in,
                              void* d_out, int out_size, void* d_ws, size_t ws_size,
                              hipStream_t stream) {
    const float* gx = (const float*)d_in[0];      // [B,S,E]
    const float* cb = (const float*)d_in[1];      // [B,S,E]
    const float* W  = (const float*)d_in[2];      // [V,E]
    const float* lg = (const float*)d_in[3];      // [B,S,V]
    float* out0 = (float*)d_out;                       // filtered, 512000 floats
    float* out1 = out0 + (size_t)BB * SS * KK;         // ids as float, 512000

    hipLaunchKernelGGL(select_ids, dim3(NROWS), dim3(256), 0, stream, lg, out1);
    hipLaunchKernelGGL(epilogue_kernel, dim3(NROWS), dim3(256), 0, stream,
                       gx, cb, W, out1, out0);
}